// Round 1
// baseline (369.971 us; speedup 1.0000x reference)
//
#include <hip/hip_runtime.h>

#define NNODES 10000
#define NEDGES 160000
#define NB 8
#define NC 32
#define EPB 8
constexpr float NEG_SLOPE = 0.01f;

__device__ __forceinline__ float sigmoidf_(float x) {
    return 1.0f / (1.0f + __expf(-x));
}

// One tiny block: fold attention weights.
// consts layout: [0:32) aq1, [32:64) ak1, [64:96) aq2, [96:128) ak2, [128] ce1, [129] ce2
__global__ __launch_bounds__(64) void precompute_kernel(
    const float* Q1, const float* K1, const float* aw1, const float* We1,
    const float* Q2, const float* K2, const float* aw2, const float* We2,
    float* consts)
{
    int t = threadIdx.x;
    if (t < 32) {
        float aq1 = 0.f, ak1 = 0.f, aq2 = 0.f, ak2 = 0.f;
        for (int s = 0; s < 32; ++s) {
            aq1 += Q1[t * 32 + s] * aw1[s];
            ak1 += K1[t * 32 + s] * aw1[32 + s];
            aq2 += Q2[t * 32 + s] * aw2[s];
            ak2 += K2[t * 32 + s] * aw2[32 + s];
        }
        consts[t]       = aq1;
        consts[32 + t]  = ak1;
        consts[64 + t]  = aq2;
        consts[96 + t]  = ak2;
        if (t == 0) {
            float ce1 = 0.f, ce2 = 0.f;
            for (int s = 0; s < 32; ++s) {
                ce1 += We1[s] * aw1[64 + s];
                ce2 += We2[s] * aw2[64 + s];
            }
            consts[128] = ce1;
            consts[129] = ce2;
        }
    }
}

// Block per node, 256 threads = 8 batch x 32 out-channel.
// xs = x @ Wn ; sq = xs . aq ; sk = xs . ak  (per node,b scalars)
// fromX: read X in [B,N,C] layout; else read xin in [N,B,C] layout (may alias xs -> in-place).
__global__ __launch_bounds__(256) void node_transform_kernel(
    const float* xin, float* xs,
    const float* __restrict__ Wn,
    const float* __restrict__ aqv, const float* __restrict__ akv,
    float* __restrict__ sq, float* __restrict__ sk,
    int fromX)
{
    __shared__ float row[NB][NC];
    int n = blockIdx.x;
    int t = threadIdx.x;
    int b = t >> 5, o = t & 31;
    float xv = fromX ? xin[(b * NNODES + n) * NC + o]
                     : xin[(n * NB + b) * NC + o];
    row[b][o] = xv;
    __syncthreads();
    float acc = 0.f;
    #pragma unroll
    for (int c = 0; c < NC; ++c) acc += row[b][c] * Wn[c * NC + o];
    xs[(n * NB + b) * NC + o] = acc;
    float vq = acc * aqv[o];
    float vk = acc * akv[o];
    #pragma unroll
    for (int m = 16; m >= 1; m >>= 1) {
        vq += __shfl_xor(vq, m, 32);
        vk += __shfl_xor(vk, m, 32);
    }
    if (o == 0) {
        sq[n * NB + b] = vq;
        sk[n * NB + b] = vk;
    }
}

// EPB edges per 256-thread block; thread = (b,o); scatter-add messages.
__global__ __launch_bounds__(256) void edge_kernel(
    const int* __restrict__ ei, const float* __restrict__ ew,
    const float* __restrict__ xs,
    const float* __restrict__ sq, const float* __restrict__ sk,
    const float* __restrict__ We, const float* __restrict__ attb,
    const float* __restrict__ cep,
    float* __restrict__ aggr)
{
    int t = threadIdx.x;
    int b = t >> 5, o = t & 31;
    float we_o = We[o];
    float ab = attb[0];
    float ce = cep[0];
    int e0 = blockIdx.x * EPB;
    #pragma unroll
    for (int i = 0; i < EPB; ++i) {
        int e = e0 + i;
        if (e >= NEDGES) break;
        int src = ei[e];
        int dst = ei[NEDGES + e];
        float w = ew[e];
        float att  = sigmoidf_(sq[src * NB + b] + sk[dst * NB + b] + w * ce + ab);
        float sige = sigmoidf_(w * we_o);
        float msg  = att * xs[(src * NB + b) * NC + o] * sige;
        atomicAdd(&aggr[(dst * NB + b) * NC + o], msg);
    }
}

// Block per node: upd = [xd, aggr] @ out_w + out_b; h = leaky(xd + upd).
// toOut: write [B,N,C] layout to final output, else [N,B,C] (may alias xd -> in-place).
__global__ __launch_bounds__(256) void update_kernel(
    const float* xd, const float* __restrict__ aggr,
    const float* __restrict__ out_w, const float* __restrict__ out_b,
    float* hout, int toOut)
{
    __shared__ float xr[NB][NC];
    __shared__ float ar[NB][NC];
    int n = blockIdx.x;
    int t = threadIdx.x;
    int b = t >> 5, o = t & 31;
    xr[b][o] = xd[(n * NB + b) * NC + o];
    ar[b][o] = aggr[(n * NB + b) * NC + o];
    __syncthreads();
    float acc = out_b[o];
    #pragma unroll
    for (int c = 0; c < NC; ++c) {
        acc += xr[b][c] * out_w[c * NC + o];
        acc += ar[b][c] * out_w[(NC + c) * NC + o];
    }
    float r = xr[b][o] + acc;
    r = (r > 0.f) ? r : NEG_SLOPE * r;
    if (toOut) hout[(b * NNODES + n) * NC + o] = r;
    else       hout[(n * NB + b) * NC + o] = r;
}

extern "C" void kernel_launch(void* const* d_in, const int* in_sizes, int n_in,
                              void* d_out, int out_size, void* d_ws, size_t ws_size,
                              hipStream_t stream) {
    const float* X    = (const float*)d_in[0];
    const int*   ei0  = (const int*)  d_in[1];
    const int*   ei1  = (const int*)  d_in[2];
    const float* ew0  = (const float*)d_in[3];
    const float* ew1  = (const float*)d_in[4];
    // d_in[5], d_in[6]: res_n_id = arange(N) (identity) -- folded away.
    const float* Wn1  = (const float*)d_in[7];
    const float* We1  = (const float*)d_in[8];
    const float* Q1   = (const float*)d_in[9];
    const float* K1   = (const float*)d_in[10];
    const float* aw1  = (const float*)d_in[11];
    const float* ab1  = (const float*)d_in[12];
    const float* ow1  = (const float*)d_in[13];
    const float* ob1  = (const float*)d_in[14];
    const float* Wn2  = (const float*)d_in[15];
    const float* We2  = (const float*)d_in[16];
    const float* Q2   = (const float*)d_in[17];
    const float* K2   = (const float*)d_in[18];
    const float* aw2  = (const float*)d_in[19];
    const float* ab2  = (const float*)d_in[20];
    const float* ow2  = (const float*)d_in[21];
    const float* ob2  = (const float*)d_in[22];

    const size_t NODE_ELEMS = (size_t)NNODES * NB * NC;   // 2,560,000
    float* A      = (float*)d_ws;                 // xs / h (in-place across phases)
    float* AG     = A + NODE_ELEMS;               // aggr
    float* SQ     = AG + NODE_ELEMS;              // [N*B]
    float* SK     = SQ + (size_t)NNODES * NB;
    float* CONSTS = SK + (size_t)NNODES * NB;     // 130 floats

    precompute_kernel<<<1, 64, 0, stream>>>(Q1, K1, aw1, We1, Q2, K2, aw2, We2, CONSTS);

    // ---- layer 1 ----
    node_transform_kernel<<<NNODES, 256, 0, stream>>>(
        X, A, Wn1, CONSTS + 0, CONSTS + 32, SQ, SK, /*fromX=*/1);
    hipMemsetAsync(AG, 0, NODE_ELEMS * sizeof(float), stream);
    edge_kernel<<<(NEDGES + EPB - 1) / EPB, 256, 0, stream>>>(
        ei0, ew0, A, SQ, SK, We1, ab1, CONSTS + 128, AG);
    update_kernel<<<NNODES, 256, 0, stream>>>(A, AG, ow1, ob1, A, /*toOut=*/0);

    // ---- layer 2 ----
    node_transform_kernel<<<NNODES, 256, 0, stream>>>(
        A, A, Wn2, CONSTS + 64, CONSTS + 96, SQ, SK, /*fromX=*/0);
    hipMemsetAsync(AG, 0, NODE_ELEMS * sizeof(float), stream);
    edge_kernel<<<(NEDGES + EPB - 1) / EPB, 256, 0, stream>>>(
        ei1, ew1, A, SQ, SK, We2, ab2, CONSTS + 129, AG);
    update_kernel<<<NNODES, 256, 0, stream>>>(A, AG, ow2, ob2, (float*)d_out, /*toOut=*/1);
}

// Round 2
// 198.239 us; speedup vs baseline: 1.8663x; 1.8663x over previous
//
#include <hip/hip_runtime.h>

#define NNODES 10000
#define NEDGES 160000
#define NB 8
#define NC 32
constexpr float NEG_SLOPE = 0.01f;

__device__ __forceinline__ float sigmoidf_(float x) {
    return 1.0f / (1.0f + __expf(-x));
}

// consts layout: [0:32) aq1, [32:64) ak1, [64:96) aq2, [96:128) ak2, [128] ce1, [129] ce2
__global__ __launch_bounds__(64) void precompute_kernel(
    const float* Q1, const float* K1, const float* aw1, const float* We1,
    const float* Q2, const float* K2, const float* aw2, const float* We2,
    float* consts)
{
    int t = threadIdx.x;
    if (t < 32) {
        float aq1 = 0.f, ak1 = 0.f, aq2 = 0.f, ak2 = 0.f;
        for (int s = 0; s < 32; ++s) {
            aq1 += Q1[t * 32 + s] * aw1[s];
            ak1 += K1[t * 32 + s] * aw1[32 + s];
            aq2 += Q2[t * 32 + s] * aw2[s];
            ak2 += K2[t * 32 + s] * aw2[32 + s];
        }
        consts[t]       = aq1;
        consts[32 + t]  = ak1;
        consts[64 + t]  = aq2;
        consts[96 + t]  = ak2;
        if (t == 0) {
            float ce1 = 0.f, ce2 = 0.f;
            for (int s = 0; s < 32; ++s) {
                ce1 += We1[s] * aw1[64 + s];
                ce2 += We2[s] * aw2[64 + s];
            }
            consts[128] = ce1;
            consts[129] = ce2;
        }
    }
}

// ---- counting sort by dst ----
__global__ __launch_bounds__(256) void hist_kernel(const int* __restrict__ ei, int* __restrict__ cnt) {
    int e = blockIdx.x * 256 + threadIdx.x;
    if (e < NEDGES) atomicAdd(&cnt[ei[NEDGES + e]], 1);
}

// single block, 1024 threads, 10 bins each: exclusive scan of cnt -> rowptr & cursor
__global__ __launch_bounds__(1024) void scan_kernel(const int* __restrict__ cnt,
                                                    int* __restrict__ rowptr,
                                                    int* __restrict__ cursor) {
    __shared__ int part[1024];
    int t = threadIdx.x;
    int base = t * 10;
    int local[10];
    int s = 0;
    #pragma unroll
    for (int i = 0; i < 10; ++i) {
        int idx = base + i;
        int v = (idx < NNODES) ? cnt[idx] : 0;
        local[i] = s;
        s += v;
    }
    part[t] = s;
    __syncthreads();
    for (int off = 1; off < 1024; off <<= 1) {
        int v = (t >= off) ? part[t - off] : 0;
        __syncthreads();
        part[t] += v;
        __syncthreads();
    }
    int pre = (t == 0) ? 0 : part[t - 1];
    #pragma unroll
    for (int i = 0; i < 10; ++i) {
        int idx = base + i;
        if (idx < NNODES) {
            int p = pre + local[i];
            rowptr[idx] = p;
            cursor[idx] = p;
        }
    }
    if (t == 1023) rowptr[NNODES] = part[1023];
}

// scatter edges into dst-sorted order, pre-gathering src and w
__global__ __launch_bounds__(256) void scatter_kernel(
    const int* __restrict__ ei, const float* __restrict__ ew,
    int* __restrict__ cursor, int* __restrict__ srcS, float* __restrict__ wS)
{
    int e = blockIdx.x * 256 + threadIdx.x;
    if (e < NEDGES) {
        int dst = ei[NEDGES + e];
        int pos = atomicAdd(&cursor[dst], 1);
        srcS[pos] = ei[e];
        wS[pos]   = ew[e];
    }
}

// Block per node: xs = x @ Wn ; sq = xs.aq ; sk = xs.ak
__global__ __launch_bounds__(256) void node_transform_kernel(
    const float* __restrict__ xin, float* __restrict__ xs,
    const float* __restrict__ Wn,
    const float* __restrict__ aqv, const float* __restrict__ akv,
    float* __restrict__ sq, float* __restrict__ sk)
{
    __shared__ float row[NB][NC];
    int n = blockIdx.x;
    int t = threadIdx.x;
    int b = t >> 5, o = t & 31;
    row[b][o] = xin[((size_t)b * NNODES + n) * NC + o];   // X is [B,N,C]
    __syncthreads();
    float acc = 0.f;
    #pragma unroll
    for (int c = 0; c < NC; ++c) acc += row[b][c] * Wn[c * NC + o];
    xs[(n * NB + b) * NC + o] = acc;
    float vq = acc * aqv[o];
    float vk = acc * akv[o];
    #pragma unroll
    for (int m = 16; m >= 1; m >>= 1) {
        vq += __shfl_xor(vq, m, 32);
        vk += __shfl_xor(vk, m, 32);
    }
    if (o == 0) {
        sq[n * NB + b] = vq;
        sk[n * NB + b] = vk;
    }
}

// Block per dst node: atomic-free gather + update GEMM + leaky.
// MODE 0: also fuse next layer's node transform (write xs2,sq2,sk2).
// MODE 1: write final output in [B,N,C].
template <int MODE>
__global__ __launch_bounds__(256) void gather_kernel(
    const int* __restrict__ rowptr, const int* __restrict__ srcS, const float* __restrict__ wS,
    const float* __restrict__ xs,
    const float* __restrict__ sq, const float* __restrict__ sk,
    const float* __restrict__ We, const float* __restrict__ attb, const float* __restrict__ cep,
    const float* __restrict__ ow, const float* __restrict__ ob,
    const float* __restrict__ Wn2, const float* __restrict__ aqv, const float* __restrict__ akv,
    float* __restrict__ xs2, float* __restrict__ sq2, float* __restrict__ sk2,
    float* __restrict__ outp)
{
    __shared__ int   srcL[32];
    __shared__ float wL[32];
    __shared__ float attL[32][NB];
    __shared__ float sigeL[32][NC];
    __shared__ float xr[NB][NC];
    __shared__ float ar[NB][NC];

    int n = blockIdx.x;
    int t = threadIdx.x;
    int b = t >> 5, o = t & 31;
    int row0 = rowptr[n];
    int deg  = rowptr[n + 1] - row0;
    float we_o = We[o];
    float ab = attb[0], ce = cep[0];
    float acc = 0.f;

    for (int c0 = 0; c0 < deg; c0 += 32) {
        int m = min(32, deg - c0);
        if (t < m) { srcL[t] = srcS[row0 + c0 + t]; wL[t] = wS[row0 + c0 + t]; }
        __syncthreads();
        {   // attL[j][bb], 32x8 = 256 threads
            int j = t >> 3, bb = t & 7;
            if (j < m) attL[j][bb] = sigmoidf_(sq[srcL[j] * NB + bb] + sk[n * NB + bb] + wL[j] * ce + ab);
        }
        #pragma unroll
        for (int r = 0; r < 4; ++r) {   // sigeL[j][o], 32x32, 4 per thread
            int j = (t >> 5) + 8 * r;
            if (j < m) sigeL[j][o] = sigmoidf_(wL[j] * we_o);
        }
        __syncthreads();
        for (int j = 0; j < m; ++j) {
            int s = srcL[j];
            acc += attL[j][b] * sigeL[j][o] * xs[(s * NB + b) * NC + o];
        }
        __syncthreads();
    }

    float xv = xs[(n * NB + b) * NC + o];
    xr[b][o] = xv;
    ar[b][o] = acc;
    __syncthreads();
    float u = ob[o];
    #pragma unroll
    for (int c = 0; c < NC; ++c) {
        u += xr[b][c] * ow[c * NC + o];
        u += ar[b][c] * ow[(NC + c) * NC + o];
    }
    float r = xv + u;
    r = (r > 0.f) ? r : NEG_SLOPE * r;

    if (MODE == 1) {
        outp[((size_t)b * NNODES + n) * NC + o] = r;
    } else {
        __syncthreads();
        ar[b][o] = r;                    // reuse as h row
        __syncthreads();
        float a2 = 0.f;
        #pragma unroll
        for (int c = 0; c < NC; ++c) a2 += ar[b][c] * Wn2[c * NC + o];
        xs2[(n * NB + b) * NC + o] = a2;
        float vq = a2 * aqv[o], vk = a2 * akv[o];
        #pragma unroll
        for (int m2 = 16; m2 >= 1; m2 >>= 1) {
            vq += __shfl_xor(vq, m2, 32);
            vk += __shfl_xor(vk, m2, 32);
        }
        if (o == 0) { sq2[n * NB + b] = vq; sk2[n * NB + b] = vk; }
    }
}

extern "C" void kernel_launch(void* const* d_in, const int* in_sizes, int n_in,
                              void* d_out, int out_size, void* d_ws, size_t ws_size,
                              hipStream_t stream) {
    const float* X    = (const float*)d_in[0];
    const int*   ei0  = (const int*)  d_in[1];
    const int*   ei1  = (const int*)  d_in[2];
    const float* ew0  = (const float*)d_in[3];
    const float* ew1  = (const float*)d_in[4];
    const float* Wn1  = (const float*)d_in[7];
    const float* We1  = (const float*)d_in[8];
    const float* Q1   = (const float*)d_in[9];
    const float* K1   = (const float*)d_in[10];
    const float* aw1  = (const float*)d_in[11];
    const float* ab1  = (const float*)d_in[12];
    const float* ow1  = (const float*)d_in[13];
    const float* ob1  = (const float*)d_in[14];
    const float* Wn2  = (const float*)d_in[15];
    const float* We2  = (const float*)d_in[16];
    const float* Q2   = (const float*)d_in[17];
    const float* K2   = (const float*)d_in[18];
    const float* aw2  = (const float*)d_in[19];
    const float* ab2  = (const float*)d_in[20];
    const float* ow2  = (const float*)d_in[21];
    const float* ob2  = (const float*)d_in[22];

    const size_t NODE_ELEMS = (size_t)NNODES * NB * NC;   // 2,560,000
    float* XS1    = (float*)d_ws;
    float* XS2    = XS1 + NODE_ELEMS;
    float* SQ1    = XS2 + NODE_ELEMS;
    float* SK1    = SQ1 + (size_t)NNODES * NB;
    float* SQ2    = SK1 + (size_t)NNODES * NB;
    float* SK2    = SQ2 + (size_t)NNODES * NB;
    float* CONSTS = SK2 + (size_t)NNODES * NB;            // 130
    int*   ROWPTR = (int*)(CONSTS + 160);
    int*   CURSOR = ROWPTR + (NNODES + 1);
    int*   SRCS   = CURSOR + NNODES;
    float* WS     = (float*)(SRCS + NEDGES);

    const int EBLKS = (NEDGES + 255) / 256;

    precompute_kernel<<<1, 64, 0, stream>>>(Q1, K1, aw1, We1, Q2, K2, aw2, We2, CONSTS);

    // ---- layer 1: sort edges by dst + node transform ----
    hipMemsetAsync(CURSOR, 0, NNODES * sizeof(int), stream);
    hist_kernel<<<EBLKS, 256, 0, stream>>>(ei0, CURSOR);
    scan_kernel<<<1, 1024, 0, stream>>>(CURSOR, ROWPTR, CURSOR);
    scatter_kernel<<<EBLKS, 256, 0, stream>>>(ei0, ew0, CURSOR, SRCS, WS);
    node_transform_kernel<<<NNODES, 256, 0, stream>>>(X, XS1, Wn1, CONSTS + 0, CONSTS + 32, SQ1, SK1);
    gather_kernel<0><<<NNODES, 256, 0, stream>>>(
        ROWPTR, SRCS, WS, XS1, SQ1, SK1, We1, ab1, CONSTS + 128, ow1, ob1,
        Wn2, CONSTS + 64, CONSTS + 96, XS2, SQ2, SK2, nullptr);

    // ---- layer 2: re-sort (reuse buffers) + gather/update/output ----
    hipMemsetAsync(CURSOR, 0, NNODES * sizeof(int), stream);
    hist_kernel<<<EBLKS, 256, 0, stream>>>(ei1, CURSOR);
    scan_kernel<<<1, 1024, 0, stream>>>(CURSOR, ROWPTR, CURSOR);
    scatter_kernel<<<EBLKS, 256, 0, stream>>>(ei1, ew1, CURSOR, SRCS, WS);
    gather_kernel<1><<<NNODES, 256, 0, stream>>>(
        ROWPTR, SRCS, WS, XS2, SQ2, SK2, We2, ab2, CONSTS + 129, ow2, ob2,
        nullptr, nullptr, nullptr, nullptr, nullptr, nullptr, (float*)d_out);
}

// Round 3
// 175.281 us; speedup vs baseline: 2.1107x; 1.1310x over previous
//
#include <hip/hip_runtime.h>

#define NNODES 10000
#define NEDGES 160000
#define NB 8
#define NC 32
#define PADE 190016   // NEDGES + 3*NNODES + slack (pad each node to multiple of 4)
constexpr float NEG_SLOPE = 0.01f;

__device__ __forceinline__ float sigmoidf_(float x) {
    return 1.0f / (1.0f + __expf(-x));
}

// consts: [0:32) aq1, [32:64) ak1, [64:96) aq2, [96:128) ak2, [128] ce1, [129] ce2
__global__ __launch_bounds__(64) void precompute_kernel(
    const float* Q1, const float* K1, const float* aw1, const float* We1,
    const float* Q2, const float* K2, const float* aw2, const float* We2,
    float* consts)
{
    int t = threadIdx.x;
    if (t < 32) {
        float aq1 = 0.f, ak1 = 0.f, aq2 = 0.f, ak2 = 0.f;
        for (int s = 0; s < 32; ++s) {
            aq1 += Q1[t * 32 + s] * aw1[s];
            ak1 += K1[t * 32 + s] * aw1[32 + s];
            aq2 += Q2[t * 32 + s] * aw2[s];
            ak2 += K2[t * 32 + s] * aw2[32 + s];
        }
        consts[t]      = aq1;
        consts[32 + t] = ak1;
        consts[64 + t] = aq2;
        consts[96 + t] = ak2;
        if (t == 0) {
            float ce1 = 0.f, ce2 = 0.f;
            for (int s = 0; s < 32; ++s) {
                ce1 += We1[s] * aw1[64 + s];
                ce2 += We2[s] * aw2[64 + s];
            }
            consts[128] = ce1;
            consts[129] = ce2;
        }
    }
}

// histogram of dst for both layers (blockIdx.y = layer)
__global__ __launch_bounds__(256) void hist_kernel(
    const int* __restrict__ ei0, const int* __restrict__ ei1, int* __restrict__ cnt01)
{
    int e = blockIdx.x * 256 + threadIdx.x;
    const int* ei = blockIdx.y ? ei1 : ei0;
    int* cnt = cnt01 + blockIdx.y * NNODES;
    if (e < NEDGES) atomicAdd(&cnt[ei[NEDGES + e]], 1);
}

// grid=2 (block per layer): exclusive scan of counts rounded UP to multiple of 4.
// cnt01 is overwritten with the start cursor (= padded start).
__global__ __launch_bounds__(1024) void scan_kernel(int* cnt01, int* rowptr01)
{
    __shared__ int part[1024];
    int layer = blockIdx.x;
    int* cnt    = cnt01 + layer * NNODES;
    int* rowptr = rowptr01 + layer * (NNODES + 1);
    int t = threadIdx.x;
    int base = t * 10;
    int local[10];
    int s = 0;
    #pragma unroll
    for (int i = 0; i < 10; ++i) {
        int idx = base + i;
        int v = (idx < NNODES) ? cnt[idx] : 0;
        int vp = (v + 3) & ~3;          // pad to multiple of 4
        local[i] = s;
        s += vp;
    }
    part[t] = s;
    __syncthreads();
    for (int off = 1; off < 1024; off <<= 1) {
        int v = (t >= off) ? part[t - off] : 0;
        __syncthreads();
        part[t] += v;
        __syncthreads();
    }
    int pre = (t == 0) ? 0 : part[t - 1];
    #pragma unroll
    for (int i = 0; i < 10; ++i) {
        int idx = base + i;
        if (idx < NNODES) {
            int p = pre + local[i];
            rowptr[idx] = p;
            cnt[idx]    = p;   // becomes scatter cursor
        }
    }
    if (t == 1023) rowptr[NNODES] = part[1023];
}

// pre-fill sorted arrays with sentinel (src=NNODES, w=0); zero the sentinel xs rows
__global__ __launch_bounds__(256) void fill_kernel(
    int* __restrict__ srcs1, int* __restrict__ srcs2,
    float* __restrict__ ws1, float* __restrict__ ws2,
    float* __restrict__ xs1, float* __restrict__ xs2)
{
    int i = blockIdx.x * 256 + threadIdx.x;
    if (i < PADE) {
        srcs1[i] = NNODES; srcs2[i] = NNODES;
        ws1[i] = 0.f;      ws2[i] = 0.f;
    }
    if (i < NB * NC) {
        xs1[(size_t)NNODES * NB * NC + i] = 0.f;
        xs2[(size_t)NNODES * NB * NC + i] = 0.f;
    }
}

// scatter edges into dst-sorted (padded) order for both layers
__global__ __launch_bounds__(256) void scatter_kernel(
    const int* __restrict__ ei0, const int* __restrict__ ei1,
    const float* __restrict__ ew0, const float* __restrict__ ew1,
    int* __restrict__ cur01,
    int* __restrict__ srcs1, int* __restrict__ srcs2,
    float* __restrict__ ws1, float* __restrict__ ws2)
{
    int e = blockIdx.x * 256 + threadIdx.x;
    int layer = blockIdx.y;
    const int*   ei = layer ? ei1 : ei0;
    const float* ew = layer ? ew1 : ew0;
    int*   cur  = cur01 + layer * NNODES;
    int*   srcs = layer ? srcs2 : srcs1;
    float* ws   = layer ? ws2 : ws1;
    if (e < NEDGES) {
        int dst = ei[NEDGES + e];
        int pos = atomicAdd(&cur[dst], 1);
        srcs[pos] = ei[e];
        ws[pos]   = ew[e];
    }
}

// wave-per-node node transform: xs = x @ Wn ; sq = xs.aq ; sk = xs.ak
// X layout [B,N,C]; xs layout [N,B,C] (float4 rows of 64).
__global__ __launch_bounds__(256) void node_transform_kernel(
    const float* __restrict__ X, float* __restrict__ xs,
    const float* __restrict__ Wn, const float* __restrict__ consts,
    float* __restrict__ sq, float* __restrict__ sk)
{
    __shared__ float wnL[NC * NC];
    __shared__ float xrow[4][NB][NC + 4];
    int t = threadIdx.x, w = t >> 6, l = t & 63, b = l >> 3, o4 = l & 7;
    int n = blockIdx.x * 4 + w;
    for (int i = t; i < NC * NC; i += 256) wnL[i] = Wn[i];
    const float4* X4 = (const float4*)X;
    float4 xv = X4[((size_t)b * NNODES + n) * 8 + o4];
    ((float4*)&xrow[w][b][0])[o4] = xv;
    __syncthreads();
    float4 aq = ((const float4*)(consts + 0))[o4];
    float4 ak = ((const float4*)(consts + 32))[o4];
    const float4* wnL4 = (const float4*)wnL;
    float4 acc = {0.f, 0.f, 0.f, 0.f};
    #pragma unroll
    for (int c = 0; c < NC; ++c) {
        float xc = xrow[w][b][c];
        float4 w4 = wnL4[c * 8 + o4];
        acc.x += xc * w4.x; acc.y += xc * w4.y;
        acc.z += xc * w4.z; acc.w += xc * w4.w;
    }
    ((float4*)xs)[(size_t)n * 64 + l] = acc;
    float vq = acc.x * aq.x + acc.y * aq.y + acc.z * aq.z + acc.w * aq.w;
    float vk = acc.x * ak.x + acc.y * ak.y + acc.z * ak.z + acc.w * ak.w;
    #pragma unroll
    for (int m = 4; m >= 1; m >>= 1) {
        vq += __shfl_xor(vq, m);
        vk += __shfl_xor(vk, m);
    }
    if (o4 == 0) {
        sq[n * NB + b] = vq;
        sk[n * NB + b] = vk;
    }
}

// Wave-per-node gather: no LDS/barriers in main loop; float4 xs loads; unroll-4.
// MODE 0: fuse layer-2 node transform (write xs2,sq2,sk2). MODE 1: final output [B,N,C].
template <int MODE>
__global__ __launch_bounds__(256) void gather_kernel(
    const int* __restrict__ rowptr, const int* __restrict__ srcs, const float* __restrict__ wsrt,
    const float* __restrict__ xs,
    const float* __restrict__ sq, const float* __restrict__ sk,
    const float* __restrict__ We, const float* __restrict__ attb,
    const float* __restrict__ consts, int ceoff,
    const float* __restrict__ ow, const float* __restrict__ ob,
    const float* __restrict__ Wn2,
    float* __restrict__ xs2, float* __restrict__ sq2, float* __restrict__ sk2,
    float* __restrict__ outp)
{
    __shared__ float owL[2 * NC * NC];                 // 8 KB
    __shared__ float wnL[(MODE == 0) ? NC * NC : 4];   // 4 KB (layer-2 fusion only)
    __shared__ float xdL[4][NB][NC + 4];
    __shared__ float arL[4][NB][NC + 4];

    int t = threadIdx.x, w = t >> 6, l = t & 63, b = l >> 3, o4 = l & 7;
    int n = blockIdx.x * 4 + w;

    for (int i = t; i < 2 * NC * NC; i += 256) owL[i] = ow[i];
    if (MODE == 0)
        for (int i = t; i < NC * NC; i += 256) wnL[i] = Wn2[i];

    float4 we4 = ((const float4*)We)[o4];
    float ab = attb[0];
    float ce = consts[ceoff];
    float skb = sk[n * NB + b];
    int row0 = rowptr[n];
    int degp = rowptr[n + 1] - row0;     // multiple of 4 (padded)
    const float4* XS4 = (const float4*)xs;
    const int*   srcp = srcs + row0;
    const float* wp   = wsrt + row0;

    float4 acc = {0.f, 0.f, 0.f, 0.f};
    for (int c0 = 0; c0 < degp; c0 += 64) {
        int idx = c0 + l;
        int   sv = (idx < degp) ? srcp[idx] : NNODES;
        float wv = (idx < degp) ? wp[idx]   : 0.f;
        int m = min(64, degp - c0);
        for (int j = 0; j < m; j += 4) {
            #pragma unroll
            for (int u = 0; u < 4; ++u) {
                int   s  = __shfl(sv, j + u);
                float wj = __shfl(wv, j + u);
                float att = sigmoidf_(sq[s * NB + b] + skb + wj * ce + ab);
                float4 x4 = XS4[(size_t)s * 64 + l];
                float4 sg;
                sg.x = sigmoidf_(wj * we4.x);
                sg.y = sigmoidf_(wj * we4.y);
                sg.z = sigmoidf_(wj * we4.z);
                sg.w = sigmoidf_(wj * we4.w);
                acc.x += att * sg.x * x4.x;
                acc.y += att * sg.y * x4.y;
                acc.z += att * sg.z * x4.z;
                acc.w += att * sg.w * x4.w;
            }
        }
    }

    // epilogue: update GEMM + residual + leaky
    float4 xv = XS4[(size_t)n * 64 + l];
    ((float4*)&xdL[w][b][0])[o4] = xv;
    ((float4*)&arL[w][b][0])[o4] = acc;
    __syncthreads();   // also covers owL/wnL staging visibility

    float4 u4 = ((const float4*)ob)[o4];
    const float4* owL4 = (const float4*)owL;
    #pragma unroll
    for (int c = 0; c < NC; ++c) {
        float xc = xdL[w][b][c];
        float ac = arL[w][b][c];
        float4 w1 = owL4[c * 8 + o4];
        float4 w2 = owL4[(NC + c) * 8 + o4];
        u4.x += xc * w1.x + ac * w2.x;
        u4.y += xc * w1.y + ac * w2.y;
        u4.z += xc * w1.z + ac * w2.z;
        u4.w += xc * w1.w + ac * w2.w;
    }
    float4 r;
    r.x = xv.x + u4.x; r.y = xv.y + u4.y; r.z = xv.z + u4.z; r.w = xv.w + u4.w;
    r.x = (r.x > 0.f) ? r.x : NEG_SLOPE * r.x;
    r.y = (r.y > 0.f) ? r.y : NEG_SLOPE * r.y;
    r.z = (r.z > 0.f) ? r.z : NEG_SLOPE * r.z;
    r.w = (r.w > 0.f) ? r.w : NEG_SLOPE * r.w;

    if (MODE == 1) {
        ((float4*)outp)[((size_t)b * NNODES + n) * 8 + o4] = r;
    } else {
        // fused layer-2 node transform (intra-wave LDS reuse; DS ops in-order per wave)
        ((float4*)&xdL[w][b][0])[o4] = r;
        float4 aq = ((const float4*)(consts + 64))[o4];
        float4 ak = ((const float4*)(consts + 96))[o4];
        const float4* wnL4 = (const float4*)wnL;
        float4 a2 = {0.f, 0.f, 0.f, 0.f};
        #pragma unroll
        for (int c = 0; c < NC; ++c) {
            float hc = xdL[w][b][c];
            float4 w4 = wnL4[c * 8 + o4];
            a2.x += hc * w4.x; a2.y += hc * w4.y;
            a2.z += hc * w4.z; a2.w += hc * w4.w;
        }
        ((float4*)xs2)[(size_t)n * 64 + l] = a2;
        float vq = a2.x * aq.x + a2.y * aq.y + a2.z * aq.z + a2.w * aq.w;
        float vk = a2.x * ak.x + a2.y * ak.y + a2.z * ak.z + a2.w * ak.w;
        #pragma unroll
        for (int m2 = 4; m2 >= 1; m2 >>= 1) {
            vq += __shfl_xor(vq, m2);
            vk += __shfl_xor(vk, m2);
        }
        if (o4 == 0) {
            sq2[n * NB + b] = vq;
            sk2[n * NB + b] = vk;
        }
    }
}

extern "C" void kernel_launch(void* const* d_in, const int* in_sizes, int n_in,
                              void* d_out, int out_size, void* d_ws, size_t ws_size,
                              hipStream_t stream) {
    const float* X    = (const float*)d_in[0];
    const int*   ei0  = (const int*)  d_in[1];
    const int*   ei1  = (const int*)  d_in[2];
    const float* ew0  = (const float*)d_in[3];
    const float* ew1  = (const float*)d_in[4];
    const float* Wn1  = (const float*)d_in[7];
    const float* We1  = (const float*)d_in[8];
    const float* Q1   = (const float*)d_in[9];
    const float* K1   = (const float*)d_in[10];
    const float* aw1  = (const float*)d_in[11];
    const float* ab1  = (const float*)d_in[12];
    const float* ow1  = (const float*)d_in[13];
    const float* ob1  = (const float*)d_in[14];
    const float* Wn2  = (const float*)d_in[15];
    const float* We2  = (const float*)d_in[16];
    const float* Q2   = (const float*)d_in[17];
    const float* K2   = (const float*)d_in[18];
    const float* aw2  = (const float*)d_in[19];
    const float* ab2  = (const float*)d_in[20];
    const float* ow2  = (const float*)d_in[21];
    const float* ob2  = (const float*)d_in[22];

    const size_t ROW = (size_t)(NNODES + 1) * NB * NC;   // 2,560,256
    float* XS1    = (float*)d_ws;
    float* XS2    = XS1 + ROW;
    float* SQ1    = XS2 + ROW;
    float* SK1    = SQ1 + (NNODES + 1) * NB;
    float* SQ2    = SK1 + (NNODES + 1) * NB;
    float* SK2    = SQ2 + (NNODES + 1) * NB;
    float* CONSTS = SK2 + (NNODES + 1) * NB;             // 160
    int* ROWPTR1  = (int*)(CONSTS + 160);
    int* ROWPTR2  = ROWPTR1 + (NNODES + 1);
    int* CNT      = ROWPTR2 + (NNODES + 1);              // 2*N (hist -> cursor)
    int* SRCS1    = CNT + 2 * NNODES;
    int* SRCS2    = SRCS1 + PADE;
    float* WS1    = (float*)(SRCS2 + PADE);
    float* WS2    = WS1 + PADE;

    const int EBLKS = (NEDGES + 255) / 256;   // 625

    hipMemsetAsync(CNT, 0, 2 * NNODES * sizeof(int), stream);
    precompute_kernel<<<1, 64, 0, stream>>>(Q1, K1, aw1, We1, Q2, K2, aw2, We2, CONSTS);
    hist_kernel<<<dim3(EBLKS, 2), 256, 0, stream>>>(ei0, ei1, CNT);
    scan_kernel<<<2, 1024, 0, stream>>>(CNT, ROWPTR1);
    fill_kernel<<<(PADE + 255) / 256, 256, 0, stream>>>(SRCS1, SRCS2, WS1, WS2, XS1, XS2);
    scatter_kernel<<<dim3(EBLKS, 2), 256, 0, stream>>>(
        ei0, ei1, ew0, ew1, CNT, SRCS1, SRCS2, WS1, WS2);
    node_transform_kernel<<<NNODES / 4, 256, 0, stream>>>(X, XS1, Wn1, CONSTS, SQ1, SK1);

    gather_kernel<0><<<NNODES / 4, 256, 0, stream>>>(
        ROWPTR1, SRCS1, WS1, XS1, SQ1, SK1, We1, ab1, CONSTS, 128, ow1, ob1,
        Wn2, XS2, SQ2, SK2, nullptr);
    gather_kernel<1><<<NNODES / 4, 256, 0, stream>>>(
        ROWPTR2, SRCS2, WS2, XS2, SQ2, SK2, We2, ab2, CONSTS, 129, ow2, ob2,
        nullptr, nullptr, nullptr, nullptr, (float*)d_out);
}